// Round 1
// baseline (802.364 us; speedup 1.0000x reference)
//
#include <hip/hip_runtime.h>
#include <hip/hip_fp16.h>

#define IN_DIM 512
#define OUT_DIM 16
#define KC 32
#define TILE_ROWS 256

// ---------------------------------------------------------------------------
// hp(fp16) = rsqrt(deg) ⊙ (x @ W) : fp32 vector GEMM, x via LDS 256x32 tiles
// (pad +1 -> 2-way bank alias, free). W loads wave-uniform -> scalar path.
// ---------------------------------------------------------------------------
__global__ __launch_bounds__(256) void gemm_xw(const float* __restrict__ x,
                                               const float* __restrict__ W,
                                               const int* __restrict__ hist,
                                               __half* __restrict__ hp, int n) {
    __shared__ float xs[TILE_ROWS * (KC + 1)];
    const int tid = threadIdx.x;
    const int rbase = blockIdx.x * TILE_ROWS;
    const int myrow = rbase + tid;

    float acc[OUT_DIM];
#pragma unroll
    for (int j = 0; j < OUT_DIM; ++j) acc[j] = 0.f;

    for (int kc = 0; kc < IN_DIM; kc += KC) {
        __syncthreads();
#pragma unroll
        for (int i = 0; i < 8; ++i) {
            const int v = tid + 256 * i;
            const int r = v >> 3;
            const int c = (v & 7) << 2;
            if (rbase + r < n) {
                const float4 f = *(const float4*)(x + (size_t)(rbase + r) * IN_DIM + kc + c);
                float* d = xs + r * (KC + 1) + c;
                d[0] = f.x; d[1] = f.y; d[2] = f.z; d[3] = f.w;
            }
        }
        __syncthreads();

        const float* xrow = xs + tid * (KC + 1);
#pragma unroll 4
        for (int k = 0; k < KC; ++k) {
            const float xv = xrow[k];
            const float* wr = W + (size_t)(kc + k) * OUT_DIM;   // uniform -> s_load
            const float4 w0 = *(const float4*)(wr + 0);
            const float4 w1 = *(const float4*)(wr + 4);
            const float4 w2 = *(const float4*)(wr + 8);
            const float4 w3 = *(const float4*)(wr + 12);
            acc[0]  += xv * w0.x; acc[1]  += xv * w0.y; acc[2]  += xv * w0.z; acc[3]  += xv * w0.w;
            acc[4]  += xv * w1.x; acc[5]  += xv * w1.y; acc[6]  += xv * w1.z; acc[7]  += xv * w1.w;
            acc[8]  += xv * w2.x; acc[9]  += xv * w2.y; acc[10] += xv * w2.z; acc[11] += xv * w2.w;
            acc[12] += xv * w3.x; acc[13] += xv * w3.y; acc[14] += xv * w3.z; acc[15] += xv * w3.w;
        }
    }

    if (myrow < n) {
        const float s = rsqrtf((float)(hist[myrow] + 1));
        __half2* op = (__half2*)(hp + (size_t)myrow * OUT_DIM);
#pragma unroll
        for (int j = 0; j < 8; ++j)
            op[j] = __floats2half2_rn(s * acc[2 * j], s * acc[2 * j + 1]);
    }
}

// in-degree histogram over targets (400 KB, device-scope int atomics)
__global__ void hist_dst(const int* __restrict__ dst, int* __restrict__ hist, int E) {
    const int e = blockIdx.x * 256 + threadIdx.x;
    if (e < E) atomicAdd(&hist[dst[e]], 1);
}

// ---------------------------------------------------------------------------
// CSR path: exclusive segment offsets via wave scan + 1 atomic per wave.
// Segment base ordering across waves is arbitrary (never need off[i+1]).
// ---------------------------------------------------------------------------
__global__ __launch_bounds__(256) void scan_off(const int* __restrict__ hist,
                                                int* __restrict__ off,
                                                int* __restrict__ cur,
                                                int* __restrict__ counter, int n) {
    const int i = blockIdx.x * 256 + threadIdx.x;
    const int lane = threadIdx.x & 63;
    const int v = (i < n) ? hist[i] : 0;
    int s = v;
#pragma unroll
    for (int d = 1; d < 64; d <<= 1) {
        const int t = __shfl_up(s, d);
        if (lane >= d) s += t;
    }
    const int waveTot = __shfl(s, 63);
    int base = 0;
    if (lane == 0) base = atomicAdd(counter, waveTot);
    base = __shfl(base, 0);
    if (i < n) {
        const int o = base + s - v;   // exclusive prefix within wave + wave base
        off[i] = o;
        cur[i] = o;
    }
}

// counting-sort edges by dst: csr[pos] = src, pos from per-dst cursor.
// 4 edges/thread -> 4 independent atomic+store chains in flight.
__global__ __launch_bounds__(256) void build_csr(const int* __restrict__ ei,
                                                 int* __restrict__ cur,
                                                 int* __restrict__ csr, int E) {
    const int t = blockIdx.x * 256 + threadIdx.x;
    const int e0 = t * 4;
    if (e0 >= E) return;
    if (e0 + 3 < E) {
        const int4 ss = *(const int4*)(ei + e0);
        const int4 dd = *(const int4*)(ei + (size_t)E + e0);
        const int p0 = atomicAdd(&cur[dd.x], 1);
        const int p1 = atomicAdd(&cur[dd.y], 1);
        const int p2 = atomicAdd(&cur[dd.z], 1);
        const int p3 = atomicAdd(&cur[dd.w], 1);
        csr[p0] = ss.x; csr[p1] = ss.y; csr[p2] = ss.z; csr[p3] = ss.w;
    } else {
        for (int e = e0; e < E; ++e) {
            const int s = ei[e];
            const int d = ei[(size_t)E + e];
            const int pos = atomicAdd(&cur[d], 1);
            csr[pos] = s;
        }
    }
}

// per dst node: 8 lanes (one __half2 feature pair each) walk the CSR segment,
// gather hp[src] (32B/edge, L2-resident table), accumulate fp32, finalize.
__global__ __launch_bounds__(256) void gather_out(const int* __restrict__ csr,
                                                  const int* __restrict__ off,
                                                  const int* __restrict__ hist,
                                                  const __half* __restrict__ hp,
                                                  const float* __restrict__ b,
                                                  float* __restrict__ out, int n) {
    const long long gid = (long long)blockIdx.x * 256 + threadIdx.x;
    const int d = (int)(gid >> 3);
    const int j2 = (int)(gid & 7);
    if (d >= n) return;

    const int base = off[d];
    const int deg = hist[d];
    const __half2* hpt = (const __half2*)hp;

    // self-loop contribution
    const __half2 sv = hpt[(size_t)d * 8 + j2];
    float ax = __low2float(sv), ay = __high2float(sv);

    int k = 0;
    for (; k + 4 <= deg; k += 4) {      // 4 independent gathers in flight
        const int s0 = csr[base + k + 0];
        const int s1 = csr[base + k + 1];
        const int s2 = csr[base + k + 2];
        const int s3 = csr[base + k + 3];
        const __half2 v0 = hpt[(size_t)s0 * 8 + j2];
        const __half2 v1 = hpt[(size_t)s1 * 8 + j2];
        const __half2 v2 = hpt[(size_t)s2 * 8 + j2];
        const __half2 v3 = hpt[(size_t)s3 * 8 + j2];
        ax += __low2float(v0) + __low2float(v1) + __low2float(v2) + __low2float(v3);
        ay += __high2float(v0) + __high2float(v1) + __high2float(v2) + __high2float(v3);
    }
    for (; k < deg; ++k) {
        const __half2 v = hpt[(size_t)csr[base + k] * 8 + j2];
        ax += __low2float(v);
        ay += __high2float(v);
    }

    const float di = rsqrtf((float)(deg + 1));
    float2 o;
    o.x = di * ax + b[2 * j2];
    o.y = di * ay + b[2 * j2 + 1];
    ((float2*)out)[(size_t)d * 8 + j2] = o;
}

// ---------------------------------------------------------------------------
// fallback path (old atomic scatter) — only if workspace can't hold the CSR
// ---------------------------------------------------------------------------
__global__ __launch_bounds__(256) void scatter_f16(const int* __restrict__ ei,
                                                   const __half* __restrict__ hp,
                                                   __half2* __restrict__ acc, int E) {
    const long long gid = (long long)blockIdx.x * 256 + threadIdx.x;
    const int g = (int)(gid >> 3);
    const int j2 = (int)(gid & 7);
    const int e0 = g * 4;
    if (e0 >= E) return;

    int src[4], dst[4];
#pragma unroll
    for (int u = 0; u < 4; ++u) {
        const int e = e0 + u;
        src[u] = (e < E) ? ei[e] : -1;
        dst[u] = (e < E) ? ei[(size_t)E + e] : -1;
    }
    __half2 v[4];
#pragma unroll
    for (int u = 0; u < 4; ++u)
        if (src[u] >= 0) v[u] = ((const __half2*)(hp + (size_t)src[u] * OUT_DIM))[j2];
#pragma unroll
    for (int u = 0; u < 4; ++u)
        if (dst[u] >= 0) unsafeAtomicAdd(&acc[(size_t)dst[u] * 8 + j2], v[u]);
}

__global__ void finalize(const __half* __restrict__ acc, const __half* __restrict__ hp,
                         const int* __restrict__ hist, const float* __restrict__ b,
                         float* __restrict__ out, int n) {
    const int gid = blockIdx.x * 256 + threadIdx.x;
    if (gid >= n * OUT_DIM) return;
    const int i = gid >> 4;
    const int j = gid & 15;
    const float di = rsqrtf((float)(hist[i] + 1));
    out[gid] = di * (__half2float(acc[gid]) + __half2float(hp[gid])) + b[j];
}

// ---------------------------------------------------------------------------

extern "C" void kernel_launch(void* const* d_in, const int* in_sizes, int n_in,
                              void* d_out, int out_size, void* d_ws, size_t ws_size,
                              hipStream_t stream) {
    const float* x  = (const float*)d_in[0];
    const int*   ei = (const int*)d_in[1];   // int inputs delivered as int32
    const float* W  = (const float*)d_in[2];
    const float* b  = (const float*)d_in[3];
    float* out = (float*)d_out;

    const int n = in_sizes[0] / IN_DIM;   // 100000
    const int E = in_sizes[1] / 2;        // 3200000

    // ws layout: hp [n*16 f16] | hist [n] | off [n] | cur [n] | counter [16] | csr [E]
    __half* hp   = (__half*)d_ws;
    int*    hist = (int*)(hp + (size_t)n * OUT_DIM);
    int*    off  = hist + n;
    int*    cur  = off + n;
    int*    cnt  = cur + n;
    int*    csr  = cnt + 16;

    const size_t need = (size_t)n * OUT_DIM * sizeof(__half)
                      + (size_t)(3 * n + 16) * sizeof(int)
                      + (size_t)E * sizeof(int);

    if (ws_size >= need) {
        hipMemsetAsync(hist, 0, (size_t)n * sizeof(int), stream);
        hipMemsetAsync(cnt, 0, sizeof(int), stream);

        hist_dst<<<(E + 255) / 256, 256, 0, stream>>>(ei + E, hist, E);
        scan_off<<<(n + 255) / 256, 256, 0, stream>>>(hist, off, cur, cnt, n);
        build_csr<<<(E / 4 + 255) / 256, 256, 0, stream>>>(ei, cur, csr, E);
        gemm_xw<<<(n + TILE_ROWS - 1) / TILE_ROWS, 256, 0, stream>>>(x, W, hist, hp, n);
        gather_out<<<((size_t)n * 8 + 255) / 256, 256, 0, stream>>>(csr, off, hist, hp, b, out, n);
    } else {
        // fallback: proven atomic-scatter path (~7.2 MB ws)
        __half* acc = (__half*)(hist + n);
        hipMemsetAsync(hist, 0, (size_t)n * sizeof(int), stream);
        hipMemsetAsync(acc, 0, (size_t)n * OUT_DIM * sizeof(__half), stream);

        hist_dst<<<(E + 255) / 256, 256, 0, stream>>>(ei + E, hist, E);
        gemm_xw<<<(n + TILE_ROWS - 1) / TILE_ROWS, 256, 0, stream>>>(x, W, hist, hp, n);
        const long long st = ((long long)(E + 3) / 4) * 8;
        scatter_f16<<<(int)((st + 255) / 256), 256, 0, stream>>>(ei, hp, (__half2*)acc, E);
        finalize<<<(n * OUT_DIM + 255) / 256, 256, 0, stream>>>(acc, hp, hist, b, out, n);
    }
}